// Round 4
// baseline (396.660 us; speedup 1.0000x reference)
//
#include <hip/hip_runtime.h>
#include <hip/hip_bf16.h>
#include <cstdint>

// AttentionPooling, fully fused single-HBM-pass over x.
// Per 64-row chunk: stage x->LDS(f16) -> MFMA scores (A from LDS, W1 in VGPRs,
// nt-split across waves) -> online softmax (wave 0) -> column accumulation
// from LDS. x is read from HBM exactly once; no L2 reliance.

#define H_DIM 256
#define HID   128
#define CHUNK 64
#define XT_STRIDE 264   // f16 per row: 256 + 8 pad (row stride 528B, 16B-aligned)

typedef _Float16 half8 __attribute__((ext_vector_type(8)));
typedef _Float16 half4 __attribute__((ext_vector_type(4)));
typedef float floatx4 __attribute__((ext_vector_type(4)));

__device__ __forceinline__ float fast_tanh(float y) {
    float e2 = __expf(2.0f * y);
    return 1.0f - 2.0f / (e2 + 1.0f);
}

// ---------------------------------------------------------------- prep_w1
// idx = ((nt*8 + ks)*64 + lane)*8 + j  <->  W1[k][n], k = ks*32+(lane>>4)*8+j,
// n = nt*16 + (lane&15)
__global__ void prep_w1(const float* __restrict__ W1, _Float16* __restrict__ w1h) {
    int idx = blockIdx.x * blockDim.x + threadIdx.x;
    if (idx >= 8 * 8 * 64 * 8) return;
    int j  = idx & 7;
    int l  = (idx >> 3) & 63;
    int ks = (idx >> 9) & 7;
    int nt = idx >> 12;
    int k = ks * 32 + ((l >> 4) << 3) + j;
    int n = nt * 16 + (l & 15);
    w1h[idx] = (_Float16)W1[k * HID + n];
}

// ---------------------------------------------------------------- fused
__global__ __launch_bounds__(256, 4) void fused_kernel(
    const float* __restrict__ x, const _Float16* __restrict__ w1h,
    const float* __restrict__ b1, const float* __restrict__ W2,
    const float* __restrict__ b2, const int* __restrict__ batch,
    float* __restrict__ out, int N)
{
    __shared__ __align__(16) _Float16 xt[CHUNK * XT_STRIDE]; // 33.8KB chunk tile
    __shared__ float pbuf[4][CHUNK];                         // per-wave score partials
    __shared__ float wbuf[CHUNK];                            // chunk exp-weights
    __shared__ float fz[2];                                  // rescale f, final Z

    int tid = threadIdx.x, b = blockIdx.x;
    int wave = tid >> 6, lane = tid & 63, g = lane >> 4, c = lane & 15;

    // segment bounds (batch sorted)
    int lo = 0, hi = N;
    while (lo < hi) { int mid = (lo + hi) >> 1; if (batch[mid] < b) lo = mid + 1; else hi = mid; }
    int start = lo; hi = N;
    while (lo < hi) { int mid = (lo + hi) >> 1; if (batch[mid] <= b) lo = mid + 1; else hi = mid; }
    int end = lo;
    int seglen = end - start;
    if (seglen <= 0) { out[(size_t)b * H_DIM + tid] = 0.0f; return; }

    // W1 B-fragments in registers: this wave owns hidden tiles nt = 2*wave+{0,1}
    half8 bfr[2][8];
#pragma unroll
    for (int nt2 = 0; nt2 < 2; ++nt2)
#pragma unroll
        for (int ks = 0; ks < 8; ++ks)
            bfr[nt2][ks] = *(const half8*)&w1h[(((2 * wave + nt2) * 8 + ks) * 64 + lane) * 8];

    float b1r[2], w2r[2];
#pragma unroll
    for (int nt2 = 0; nt2 < 2; ++nt2) {
        b1r[nt2] = b1[(2 * wave + nt2) * 16 + c];
        w2r[nt2] = W2[(2 * wave + nt2) * 16 + c];
    }
    float b2v = b2[0];

    float m_run = -3.0e38f;   // wave0-uniform running max
    float Zrun  = 0.0f;       // wave0-uniform running Z
    float accv  = 0.0f;       // per-thread column accumulator

    for (int co = 0; co < seglen; co += CHUNK) {
        int cnt = min(CHUNK, seglen - co);

        __syncthreads();   // S1: prev accumulation reads of xt complete

        // ---- stage: chunk rows -> f16 LDS tile (two batches of 8 float4/thread)
#pragma unroll
        for (int hb = 0; hb < 2; ++hb) {
            float4 rv[8];
#pragma unroll
            for (int i = 0; i < 8; ++i) {
                int fi = tid + (hb * 8 + i) * 256;       // 0..4095 float4 slots
                int row = fi >> 6, col4 = fi & 63;
                int rr = row < cnt ? row : cnt - 1;      // clamp tail: finite dup
                rv[i] = *(const float4*)(x + (size_t)(start + co + rr) * H_DIM + col4 * 4);
            }
#pragma unroll
            for (int i = 0; i < 8; ++i) {
                int fi = tid + (hb * 8 + i) * 256;
                int row = fi >> 6, col4 = fi & 63;
                half4 hv;
                hv[0] = (_Float16)rv[i].x; hv[1] = (_Float16)rv[i].y;
                hv[2] = (_Float16)rv[i].z; hv[3] = (_Float16)rv[i].w;
                *(half4*)&xt[row * XT_STRIDE + col4 * 4] = hv;
            }
        }

        __syncthreads();   // S2: xt ready

        // ---- scores: 4 m-tiles x 2 n-tiles per wave, K=256 in 8 steps
        floatx4 acc[4][2];
#pragma unroll
        for (int mt = 0; mt < 4; ++mt)
#pragma unroll
            for (int nt2 = 0; nt2 < 2; ++nt2)
#pragma unroll
                for (int q = 0; q < 4; ++q) acc[mt][nt2][q] = 0.0f;

#pragma unroll
        for (int ks = 0; ks < 8; ++ks) {
#pragma unroll
            for (int mt = 0; mt < 4; ++mt) {
                half8 af = *(const half8*)&xt[(mt * 16 + c) * XT_STRIDE + ks * 32 + g * 8];
                acc[mt][0] = __builtin_amdgcn_mfma_f32_16x16x32_f16(af, bfr[0][ks], acc[mt][0], 0, 0, 0);
                acc[mt][1] = __builtin_amdgcn_mfma_f32_16x16x32_f16(af, bfr[1][ks], acc[mt][1], 0, 0, 0);
            }
        }

        // ---- epilogue: partial score over this wave's 32 hidden units
        // D layout: col c = hidden within tile, row = g*4 + r within m-tile
#pragma unroll
        for (int mt = 0; mt < 4; ++mt) {
#pragma unroll
            for (int r = 0; r < 4; ++r) {
                float p = fast_tanh(acc[mt][0][r] + b1r[0]) * w2r[0]
                        + fast_tanh(acc[mt][1][r] + b1r[1]) * w2r[1];
                p += __shfl_xor(p, 8);
                p += __shfl_xor(p, 4);
                p += __shfl_xor(p, 2);
                p += __shfl_xor(p, 1);
                if (c == 0) pbuf[wave][mt * 16 + g * 4 + r] = p;
            }
        }

        __syncthreads();   // S3: pbuf ready

        // ---- online softmax update (wave 0; lane = chunk row)
        if (wave == 0) {
            float sv = (lane < cnt)
                ? (pbuf[0][lane] + pbuf[1][lane] + pbuf[2][lane] + pbuf[3][lane] + b2v)
                : -3.0e38f;
            float cm = sv;
#pragma unroll
            for (int off = 32; off; off >>= 1) cm = fmaxf(cm, __shfl_xor(cm, off));
            float m_new = fmaxf(m_run, cm);
            float f = __expf(m_run - m_new);      // 0 on first chunk
            float w = __expf(sv - m_new);         // 0 for masked rows
            wbuf[lane] = w;
            float sw = w;
#pragma unroll
            for (int off = 32; off; off >>= 1) sw += __shfl_xor(sw, off);
            Zrun = Zrun * f + sw;
            m_run = m_new;
            if (lane == 0) fz[0] = f;
        }

        __syncthreads();   // S4: wbuf / fz[0] ready

        // ---- accumulation: thread t owns column t; rows from LDS (f16)
        float f = fz[0];
        float a = 0.0f;
#pragma unroll 8
        for (int j = 0; j < CHUNK; ++j)
            a = fmaf(wbuf[j], (float)xt[j * XT_STRIDE + tid], a);
        accv = accv * f + a;
    }

    if (tid == 0) fz[1] = Zrun;
    __syncthreads();
    out[(size_t)b * H_DIM + tid] = accv / fz[1];
}

// ---------------------------------------------------------------- launch
extern "C" void kernel_launch(void* const* d_in, const int* in_sizes, int n_in,
                              void* d_out, int out_size, void* d_ws, size_t ws_size,
                              hipStream_t stream) {
    const float* x    = (const float*)d_in[0];
    const float* W1   = (const float*)d_in[1];
    const float* b1   = (const float*)d_in[2];
    const float* W2   = (const float*)d_in[3];
    const float* b2   = (const float*)d_in[4];
    const int*   batch = (const int*)d_in[5];
    int N = in_sizes[5];
    int B = out_size / H_DIM;

    _Float16* w1h = (_Float16*)d_ws;   // 64KB frag-ordered W1

    prep_w1<<<32768 / 256, 256, 0, stream>>>(W1, w1h);
    fused_kernel<<<B, 256, 0, stream>>>(x, w1h, b1, W2, b2, batch, (float*)d_out, N);
}